// Round 25
// baseline (288.229 us; speedup 1.0000x reference)
//
#include <hip/hip_runtime.h>

#define S 512
#define Dm 512
#define NBLK 256

typedef __bf16 bf16x8 __attribute__((ext_vector_type(8)));
typedef float f32x4 __attribute__((ext_vector_type(4)));
typedef _Float16 half_t;
typedef half_t h2 __attribute__((ext_vector_type(2)));
typedef half_t h4 __attribute__((ext_vector_type(4)));

static __device__ __forceinline__ h2 habs2(h2 x) {
    unsigned u = __builtin_bit_cast(unsigned, x) & 0x7FFF7FFFu;
    return __builtin_bit_cast(h2, u);
}
static __device__ __forceinline__ h2 hmax2(h2 a, h2 b) {
    h2 r;
    asm("v_pk_max_f16 %0, %1, %2" : "=v"(r) : "v"(a), "v"(b));
    return r;
}

// device-scope grid barrier: capacity-guaranteed co-residency (256 blocks <= 256 CUs)
static __device__ __forceinline__ void grid_bar(unsigned* cnt, int idx) {
    __threadfence();                    // my writes visible device-wide
    __syncthreads();                    // whole block done
    if (threadIdx.x == 0) {
        atomicAdd(&cnt[idx], 1u);
        while (atomicAdd(&cnt[idx], 0u) < (unsigned)NBLK)
            __builtin_amdgcn_s_sleep(8);
    }
    __syncthreads();
    __threadfence();                    // others' writes visible to me
}

// One kernel, 256 blocks x 512 threads (1 block/CU), 4 phases + 3 spin barriers.
__global__ __launch_bounds__(512) void mega_kernel(
    const float* __restrict__ hs,
    const float* __restrict__ Wq, const float* __restrict__ bq,
    const float* __restrict__ Wk, const float* __restrict__ bk,
    const float* __restrict__ Wv, const float* __restrict__ bv,
    const float* __restrict__ Wo, const float* __restrict__ bo,
    const float* __restrict__ mask, const float* __restrict__ gamma,
    const float* __restrict__ alpha,
    __bf16* __restrict__ Abf,
    __bf16* __restrict__ T0, __bf16* __restrict__ T1,
    __bf16* __restrict__ T2, __bf16* __restrict__ T3,
    half_t* __restrict__ QT, half_t* __restrict__ KT, half_t* __restrict__ V16,
    __bf16* __restrict__ Cbf, float* __restrict__ out,
    unsigned* __restrict__ cnt)
{
    int blk = blockIdx.x;
    int u = threadIdx.x;

    __shared__ char smem[24832];
    __bf16 (*Tl)[72]       = (__bf16 (*)[72])smem;            // phase 0 (9216 B)
    half_t (*zs)[8]        = (half_t (*)[8])smem;             // phase 2 (8192 B)
    float  (*zpart)[8]     = (float (*)[8])(smem + 8192);     // 256 B
    float  (*part)[8][64]  = (float (*)[8][64])(smem + 8448); // 16384 B

    // ================= phase 0: prep =================
    if (u < 128) {                       // hs -> bf16, 1/256th per block
        int i = (blk * 128 + u) * 8;
        float4 x0 = *(const float4*)(hs + i);
        float4 x1 = *(const float4*)(hs + i + 4);
        bf16x8 y;
        y[0] = (__bf16)x0.x; y[1] = (__bf16)x0.y; y[2] = (__bf16)x0.z; y[3] = (__bf16)x0.w;
        y[4] = (__bf16)x1.x; y[5] = (__bf16)x1.y; y[6] = (__bf16)x1.z; y[7] = (__bf16)x1.w;
        *(bf16x8*)(Abf + i) = y;
    }
    {                                    // one 64x64 W-tile per block
        int m = blk >> 6;
        int t = blk & 63;
        const float* W = (m == 0) ? Wq : (m == 1) ? Wk : (m == 2) ? Wv : Wo;
        __bf16* T = (m == 0) ? T0 : (m == 1) ? T1 : (m == 2) ? T2 : T3;
        int k0 = (t >> 3) << 6;
        int n0 = (t & 7) << 6;
        {
            int kk = u >> 4;             // 0..31
            int n4 = (u & 15) << 2;
            #pragma unroll
            for (int p = 0; p < 2; ++p) {
                int k = kk + (p << 5);
                float4 wv = *(const float4*)(W + (k0 + k) * Dm + n0 + n4);
                Tl[n4 + 0][k] = (__bf16)wv.x;
                Tl[n4 + 1][k] = (__bf16)wv.y;
                Tl[n4 + 2][k] = (__bf16)wv.z;
                Tl[n4 + 3][k] = (__bf16)wv.w;
            }
        }
        __syncthreads();
        {
            int n = u >> 3;              // 0..63
            int ks = (u & 7) << 3;       // 0..56
            uint4 d0 = *(const uint4*)&Tl[n][ks];
            *(uint4*)(T + (n0 + n) * Dm + k0 + ks) = d0;
        }
    }
    grid_bar(cnt, 0);

    // ================= phase 1: QKV GEMM (768 tiles, 512 engines of 256 thr) =================
    {
        int eng = (blk << 1) | (u >> 8);
        int ul = u & 255;
        int w4 = ul >> 6, lane = ul & 63;
        int r = lane & 15, kg = lane >> 4;

        for (int t = eng; t < 768; t += 512) {
            int m = t >> 8;
            int tile = t & 255;
            const __bf16* T = (m == 0) ? T0 : (m == 1) ? T1 : T2;
            const float* bias = (m == 0) ? bq : (m == 1) ? bk : bv;
            int rt = tile >> 4, ct = tile & 15;
            int row0 = (rt << 5) + ((w4 >> 1) << 4);
            int col0 = (ct << 5) + ((w4 & 1) << 4);

            const __bf16* Ap = Abf + (row0 + r) * Dm + (kg << 3);
            const __bf16* Bp = T + (col0 + r) * Dm + (kg << 3);

            f32x4 acc = {0.f, 0.f, 0.f, 0.f};
            #pragma unroll 4
            for (int k0 = 0; k0 < Dm; k0 += 32) {
                bf16x8 a = *(const bf16x8*)(Ap + k0);
                bf16x8 b = *(const bf16x8*)(Bp + k0);
                acc = __builtin_amdgcn_mfma_f32_16x16x32_bf16(a, b, acc, 0, 0, 0);
            }

            int orow = row0 + (kg << 2);
            float bb = bias[col0 + r];
            if (m < 2) {
                half_t* O = (m == 0) ? QT : KT;
                h4 o;
                o[0] = (half_t)(acc[0] + bb);
                o[1] = (half_t)(acc[1] + bb);
                o[2] = (half_t)(acc[2] + bb);
                o[3] = (half_t)(acc[3] + bb);
                *(h4*)(O + (col0 + r) * S + orow) = o;
            } else {
                #pragma unroll
                for (int tt = 0; tt < 4; ++tt)
                    V16[(orow + tt) * Dm + col0 + r] = (half_t)(acc[tt] + bb);
            }
        }
    }
    grid_bar(cnt, 1);

    // ================= phase 2: fused z' + ctx (2 logical blocks) =================
    {
        int w = u >> 6, lane = u & 63;
        int jj = (w << 6) + lane;
        float sc = 1.0f / (gamma[0] * 8.0f);
        float al = alpha[0];
        float madd = (1.0f - mask[jj]) * 1e6f;

        #pragma unroll 1
        for (int sub = 0; sub < 2; ++sub) {
            int lb = (blk << 1) + sub;
            int h  = lb >> 6;
            int it = lb & 63;
            int i0 = it << 3;
            int c0 = h << 6;

            __syncthreads();             // LDS reuse across sub-iterations

            const half_t* kcol = KT + (c0 * S) + jj;
            const half_t* qrow = QT + (c0 * S) + i0;

            h2 acc2[4] = {};
            #pragma unroll 8
            for (int d = 0; d < 64; ++d) {
                half_t kh = kcol[d * S];
                h2 k2 = {kh, kh};
                uint4 qu = *(const uint4*)(qrow + d * S);
                acc2[0] += habs2(__builtin_bit_cast(h2, qu.x) - k2);
                acc2[1] += habs2(__builtin_bit_cast(h2, qu.y) - k2);
                acc2[2] += habs2(__builtin_bit_cast(h2, qu.z) - k2);
                acc2[3] += habs2(__builtin_bit_cast(h2, qu.w) - k2);
            }

            float zrs[8];
            h4 zlo, zhi;
            #pragma unroll
            for (int p = 0; p < 4; ++p) {
                float s0 = (float)acc2[p].x;
                float s1 = (float)acc2[p].y;
                float z0 = fminf(fmaxf(s0 * sc - al, 0.0f) + madd, 64.0f);
                float z1 = fminf(fmaxf(s1 * sc - al, 0.0f) + madd, 64.0f);
                half_t h0 = (half_t)z0, h1 = (half_t)z1;
                if (p < 2) { zlo[2 * p] = h0; zlo[2 * p + 1] = h1; }
                else       { zhi[2 * (p - 2)] = h0; zhi[2 * (p - 2) + 1] = h1; }
                zrs[2 * p] = (float)h0;
                zrs[2 * p + 1] = (float)h1;
            }
            *(h4*)&zs[jj][0] = zlo;
            *(h4*)&zs[jj][4] = zhi;

            #pragma unroll
            for (int r = 0; r < 8; ++r) {
                float v = zrs[r];
                v += __shfl_xor(v, 1, 64);
                v += __shfl_xor(v, 2, 64);
                v += __shfl_xor(v, 4, 64);
                v += __shfl_xor(v, 8, 64);
                v += __shfl_xor(v, 16, 64);
                v += __shfl_xor(v, 32, 64);
                zrs[r] = v;
            }
            if (lane == 0) {
                #pragma unroll
                for (int r = 0; r < 8; ++r) zpart[w][r] = zrs[r];
            }
            __syncthreads();

            int wu = __builtin_amdgcn_readfirstlane(w);
            float accB[8] = {};

            #pragma unroll
            for (int cch = 0; cch < 4; ++cch) {
                int jg = (cch << 7) + (wu << 4);
                h2 c2[4] = {};
                #pragma unroll
                for (int t = 0; t < 16; ++t) {
                    half_t vh = V16[(jg + t) * Dm + c0 + lane];
                    h2 v2 = {vh, vh};
                    uint4 zu = *(const uint4*)&zs[jg + t][0];
                    c2[0] += hmax2(v2, __builtin_bit_cast(h2, zu.x));
                    c2[1] += hmax2(v2, __builtin_bit_cast(h2, zu.y));
                    c2[2] += hmax2(v2, __builtin_bit_cast(h2, zu.z));
                    c2[3] += hmax2(v2, __builtin_bit_cast(h2, zu.w));
                }
                #pragma unroll
                for (int p = 0; p < 4; ++p) {
                    accB[2 * p]     += (float)c2[p].x;
                    accB[2 * p + 1] += (float)c2[p].y;
                }
            }

            #pragma unroll
            for (int ii = 0; ii < 8; ++ii)
                part[w][ii][lane] = accB[ii];
            __syncthreads();

            {
                int ii = u >> 6;
                float s = 0.f;
                #pragma unroll
                for (int ww = 0; ww < 8; ++ww) s += part[ww][ii][lane];
                float zsum = 0.f;
                #pragma unroll
                for (int p = 0; p < 8; ++p) zsum += zpart[p][ii];
                Cbf[(i0 + ii) * Dm + c0 + lane] = (__bf16)(s - zsum);
            }
        }
    }
    grid_bar(cnt, 2);

    // ================= phase 3: output projection (256 tiles) =================
    {
        int eng = (blk << 1) | (u >> 8);
        if (eng < 256) {
            int ul = u & 255;
            int w4 = ul >> 6, lane = ul & 63;
            int r = lane & 15, kg = lane >> 4;
            int rt = eng >> 4, ct = eng & 15;
            int row0 = (rt << 5) + ((w4 >> 1) << 4);
            int col0 = (ct << 5) + ((w4 & 1) << 4);

            const __bf16* Ap = Cbf + (row0 + r) * Dm + (kg << 3);
            const __bf16* Bp = T3 + (col0 + r) * Dm + (kg << 3);

            f32x4 acc = {0.f, 0.f, 0.f, 0.f};
            #pragma unroll 4
            for (int k0 = 0; k0 < Dm; k0 += 32) {
                bf16x8 a = *(const bf16x8*)(Ap + k0);
                bf16x8 b = *(const bf16x8*)(Bp + k0);
                acc = __builtin_amdgcn_mfma_f32_16x16x32_bf16(a, b, acc, 0, 0, 0);
            }

            int orow = row0 + (kg << 2);
            float bb = bo[col0 + r];
            #pragma unroll
            for (int t = 0; t < 4; ++t)
                out[(orow + t) * Dm + col0 + r] = acc[t] + bb;
        }
    }
}

extern "C" void kernel_launch(void* const* d_in, const int* in_sizes, int n_in,
                              void* d_out, int out_size, void* d_ws, size_t ws_size,
                              hipStream_t stream) {
    const float* hs    = (const float*)d_in[0];
    const float* mask  = (const float*)d_in[1];
    const float* Wq    = (const float*)d_in[2];
    const float* bq    = (const float*)d_in[3];
    const float* Wk    = (const float*)d_in[4];
    const float* bk    = (const float*)d_in[5];
    const float* Wv    = (const float*)d_in[6];
    const float* bv    = (const float*)d_in[7];
    const float* Wo    = (const float*)d_in[8];
    const float* bo    = (const float*)d_in[9];
    const float* gamma = (const float*)d_in[10];
    const float* alpha = (const float*)d_in[11];
    float* out = (float*)d_out;

    char* base = (char*)d_ws;
    half_t* QT  = (half_t*)(base);                     // 0.5 MB
    half_t* KT  = QT + S * Dm;                         // 0.5 MB
    half_t* V16 = KT + S * Dm;                         // 0.5 MB
    __bf16* Abf = (__bf16*)(V16 + S * Dm);             // 0.5 MB
    __bf16* T0  = Abf + S * Dm;                        // 0.5 MB each
    __bf16* T1  = T0 + S * Dm;
    __bf16* T2  = T1 + S * Dm;
    __bf16* T3  = T2 + S * Dm;
    __bf16* Cbf = T3 + S * Dm;                         // 0.5 MB
    unsigned* cnt = (unsigned*)(base + (5u << 20));    // barrier counters

    hipMemsetAsync(cnt, 0, 4 * sizeof(unsigned), stream);
    hipLaunchKernelGGL(mega_kernel, dim3(NBLK), dim3(512), 0, stream,
                       hs, Wq, bq, Wk, bk, Wv, bv, Wo, bo,
                       mask, gamma, alpha,
                       Abf, T0, T1, T2, T3, QT, KT, V16, Cbf, out, cnt);
}

// Round 26
// 222.340 us; speedup vs baseline: 1.2963x; 1.2963x over previous
//
#include <hip/hip_runtime.h>

#define S 512
#define Dm 512
#define NBLK 512

typedef __bf16 bf16x8 __attribute__((ext_vector_type(8)));
typedef float f32x4 __attribute__((ext_vector_type(4)));
typedef _Float16 half_t;
typedef half_t h2 __attribute__((ext_vector_type(2)));
typedef half_t h4 __attribute__((ext_vector_type(4)));

static __device__ __forceinline__ h2 habs2(h2 x) {
    unsigned u = __builtin_bit_cast(unsigned, x) & 0x7FFF7FFFu;
    return __builtin_bit_cast(h2, u);
}
static __device__ __forceinline__ h2 hmax2(h2 a, h2 b) {
    h2 r;
    asm("v_pk_max_f16 %0, %1, %2" : "=v"(r) : "v"(a), "v"(b));
    return r;
}

// grid barrier: fetch_add arrival + LOAD-based poll (no RMW contention).
static __device__ __forceinline__ void grid_bar(unsigned* cnt, int idx) {
    __syncthreads();
    if (threadIdx.x == 0) {
        __hip_atomic_fetch_add(&cnt[idx], 1u, __ATOMIC_ACQ_REL, __HIP_MEMORY_SCOPE_AGENT);
        while (__hip_atomic_load(&cnt[idx], __ATOMIC_ACQUIRE, __HIP_MEMORY_SCOPE_AGENT)
               < (unsigned)NBLK)
            __builtin_amdgcn_s_sleep(16);
    }
    __syncthreads();
}

// One kernel, 512 blocks x 512 threads, exactly 2 blocks/CU (capacity-guaranteed).
__global__ __launch_bounds__(512, 4) void mega_kernel(
    const float* __restrict__ hs,
    const float* __restrict__ Wq, const float* __restrict__ bq,
    const float* __restrict__ Wk, const float* __restrict__ bk,
    const float* __restrict__ Wv, const float* __restrict__ bv,
    const float* __restrict__ Wo, const float* __restrict__ bo,
    const float* __restrict__ mask, const float* __restrict__ gamma,
    const float* __restrict__ alpha,
    __bf16* __restrict__ Abf,
    __bf16* __restrict__ T0, __bf16* __restrict__ T1,
    __bf16* __restrict__ T2, __bf16* __restrict__ T3,
    half_t* __restrict__ QT, half_t* __restrict__ KT, half_t* __restrict__ V16,
    __bf16* __restrict__ Cbf, float* __restrict__ out,
    unsigned* __restrict__ cnt)
{
    int blk = blockIdx.x;
    int u = threadIdx.x;

    __shared__ char smem[24832];
    __bf16 (*Tl)[72]      = (__bf16 (*)[72])smem;            // phase 0 (9216 B)
    half_t (*zs)[8]       = (half_t (*)[8])smem;             // phase 2 (8192 B)
    float  (*zpart)[8]    = (float (*)[8])(smem + 8192);     // 256 B
    float  (*part)[8][64] = (float (*)[8][64])(smem + 8448); // 16384 B

    // ================= phase 0: prep =================
    if (blk < 64) {                      // hs -> bf16: 64 blocks x 512 thr x 8
        int i = (blk * 512 + u) * 8;
        float4 x0 = *(const float4*)(hs + i);
        float4 x1 = *(const float4*)(hs + i + 4);
        bf16x8 y;
        y[0] = (__bf16)x0.x; y[1] = (__bf16)x0.y; y[2] = (__bf16)x0.z; y[3] = (__bf16)x0.w;
        y[4] = (__bf16)x1.x; y[5] = (__bf16)x1.y; y[6] = (__bf16)x1.z; y[7] = (__bf16)x1.w;
        *(bf16x8*)(Abf + i) = y;
    }
    if (blk < 256) {                     // one 64x64 W-tile per block
        int m = blk >> 6;
        int t = blk & 63;
        const float* W = (m == 0) ? Wq : (m == 1) ? Wk : (m == 2) ? Wv : Wo;
        __bf16* T = (m == 0) ? T0 : (m == 1) ? T1 : (m == 2) ? T2 : T3;
        int k0 = (t >> 3) << 6;
        int n0 = (t & 7) << 6;
        {
            int kk = u >> 3;             // 0..63
            int n4 = (u & 7) << 3;       // 0..56
            const float* wp = W + (k0 + kk) * Dm + n0 + n4;
            float4 w0v = *(const float4*)(wp);
            float4 w1v = *(const float4*)(wp + 4);
            Tl[n4 + 0][kk] = (__bf16)w0v.x;
            Tl[n4 + 1][kk] = (__bf16)w0v.y;
            Tl[n4 + 2][kk] = (__bf16)w0v.z;
            Tl[n4 + 3][kk] = (__bf16)w0v.w;
            Tl[n4 + 4][kk] = (__bf16)w1v.x;
            Tl[n4 + 5][kk] = (__bf16)w1v.y;
            Tl[n4 + 6][kk] = (__bf16)w1v.z;
            Tl[n4 + 7][kk] = (__bf16)w1v.w;
        }
        __syncthreads();
        {
            int n = u >> 3;              // 0..63
            int ks = (u & 7) << 3;       // 0..56
            uint4 d0 = *(const uint4*)&Tl[n][ks];
            *(uint4*)(T + (n0 + n) * Dm + k0 + ks) = d0;
        }
    }
    grid_bar(cnt, 0);

    // ================= phase 1: QKV GEMM (768 tiles, 1024 engines of 256 thr) =================
    {
        int eng = (blk << 1) | (u >> 8);
        if (eng < 768) {
            int ul = u & 255;
            int w4 = ul >> 6, lane = ul & 63;
            int r = lane & 15, kg = lane >> 4;

            int m = eng >> 8;
            int tile = eng & 255;
            const __bf16* T = (m == 0) ? T0 : (m == 1) ? T1 : T2;
            const float* bias = (m == 0) ? bq : (m == 1) ? bk : bv;
            int rt = tile >> 4, ct = tile & 15;
            int row0 = (rt << 5) + ((w4 >> 1) << 4);
            int col0 = (ct << 5) + ((w4 & 1) << 4);

            const __bf16* Ap = Abf + (row0 + r) * Dm + (kg << 3);
            const __bf16* Bp = T + (col0 + r) * Dm + (kg << 3);

            f32x4 acc = {0.f, 0.f, 0.f, 0.f};
            #pragma unroll 4
            for (int k0 = 0; k0 < Dm; k0 += 32) {
                bf16x8 a = *(const bf16x8*)(Ap + k0);
                bf16x8 b = *(const bf16x8*)(Bp + k0);
                acc = __builtin_amdgcn_mfma_f32_16x16x32_bf16(a, b, acc, 0, 0, 0);
            }

            int orow = row0 + (kg << 2);
            float bb = bias[col0 + r];
            if (m < 2) {
                half_t* O = (m == 0) ? QT : KT;
                h4 o;
                o[0] = (half_t)(acc[0] + bb);
                o[1] = (half_t)(acc[1] + bb);
                o[2] = (half_t)(acc[2] + bb);
                o[3] = (half_t)(acc[3] + bb);
                *(h4*)(O + (col0 + r) * S + orow) = o;
            } else {
                #pragma unroll
                for (int tt = 0; tt < 4; ++tt)
                    V16[(orow + tt) * Dm + col0 + r] = (half_t)(acc[tt] + bb);
            }
        }
    }
    grid_bar(cnt, 1);

    // ================= phase 2: fused z' + ctx (identical geometry to r24) =================
    {
        int w = u >> 6, lane = u & 63;
        int jj = (w << 6) + lane;
        int h  = blk >> 6;
        int it = blk & 63;
        int i0 = it << 3;
        int c0 = h << 6;

        float sc = 1.0f / (gamma[0] * 8.0f);
        float al = alpha[0];
        float madd = (1.0f - mask[jj]) * 1e6f;

        const half_t* kcol = KT + (c0 * S) + jj;
        const half_t* qrow = QT + (c0 * S) + i0;

        h2 acc2[4] = {};
        #pragma unroll 8
        for (int d = 0; d < 64; ++d) {
            half_t kh = kcol[d * S];
            h2 k2 = {kh, kh};
            uint4 qu = *(const uint4*)(qrow + d * S);
            acc2[0] += habs2(__builtin_bit_cast(h2, qu.x) - k2);
            acc2[1] += habs2(__builtin_bit_cast(h2, qu.y) - k2);
            acc2[2] += habs2(__builtin_bit_cast(h2, qu.z) - k2);
            acc2[3] += habs2(__builtin_bit_cast(h2, qu.w) - k2);
        }

        float zrs[8];
        h4 zlo, zhi;
        #pragma unroll
        for (int p = 0; p < 4; ++p) {
            float s0 = (float)acc2[p].x;
            float s1 = (float)acc2[p].y;
            float z0 = fminf(fmaxf(s0 * sc - al, 0.0f) + madd, 64.0f);
            float z1 = fminf(fmaxf(s1 * sc - al, 0.0f) + madd, 64.0f);
            half_t h0 = (half_t)z0, h1 = (half_t)z1;
            if (p < 2) { zlo[2 * p] = h0; zlo[2 * p + 1] = h1; }
            else       { zhi[2 * (p - 2)] = h0; zhi[2 * (p - 2) + 1] = h1; }
            zrs[2 * p] = (float)h0;
            zrs[2 * p + 1] = (float)h1;
        }
        *(h4*)&zs[jj][0] = zlo;
        *(h4*)&zs[jj][4] = zhi;

        #pragma unroll
        for (int r = 0; r < 8; ++r) {
            float v = zrs[r];
            v += __shfl_xor(v, 1, 64);
            v += __shfl_xor(v, 2, 64);
            v += __shfl_xor(v, 4, 64);
            v += __shfl_xor(v, 8, 64);
            v += __shfl_xor(v, 16, 64);
            v += __shfl_xor(v, 32, 64);
            zrs[r] = v;
        }
        if (lane == 0) {
            #pragma unroll
            for (int r = 0; r < 8; ++r) zpart[w][r] = zrs[r];
        }
        __syncthreads();

        int wu = __builtin_amdgcn_readfirstlane(w);
        float accB[8] = {};

        #pragma unroll
        for (int cch = 0; cch < 4; ++cch) {
            int jg = (cch << 7) + (wu << 4);
            h2 c2[4] = {};
            #pragma unroll
            for (int t = 0; t < 16; ++t) {
                half_t vh = V16[(jg + t) * Dm + c0 + lane];
                h2 v2 = {vh, vh};
                uint4 zu = *(const uint4*)&zs[jg + t][0];
                c2[0] += hmax2(v2, __builtin_bit_cast(h2, zu.x));
                c2[1] += hmax2(v2, __builtin_bit_cast(h2, zu.y));
                c2[2] += hmax2(v2, __builtin_bit_cast(h2, zu.z));
                c2[3] += hmax2(v2, __builtin_bit_cast(h2, zu.w));
            }
            #pragma unroll
            for (int p = 0; p < 4; ++p) {
                accB[2 * p]     += (float)c2[p].x;
                accB[2 * p + 1] += (float)c2[p].y;
            }
        }

        #pragma unroll
        for (int ii = 0; ii < 8; ++ii)
            part[w][ii][lane] = accB[ii];
        __syncthreads();

        {
            int ii = u >> 6;
            float s = 0.f;
            #pragma unroll
            for (int ww = 0; ww < 8; ++ww) s += part[ww][ii][lane];
            float zsum = 0.f;
            #pragma unroll
            for (int p = 0; p < 8; ++p) zsum += zpart[p][ii];
            Cbf[(i0 + ii) * Dm + c0 + lane] = (__bf16)(s - zsum);
        }
    }
    grid_bar(cnt, 2);

    // ================= phase 3: output projection (256 engines) =================
    {
        int eng = (blk << 1) | (u >> 8);
        if (eng < 256) {
            int ul = u & 255;
            int w4 = ul >> 6, lane = ul & 63;
            int r = lane & 15, kg = lane >> 4;
            int rt = eng >> 4, ct = eng & 15;
            int row0 = (rt << 5) + ((w4 >> 1) << 4);
            int col0 = (ct << 5) + ((w4 & 1) << 4);

            const __bf16* Ap = Cbf + (row0 + r) * Dm + (kg << 3);
            const __bf16* Bp = T3 + (col0 + r) * Dm + (kg << 3);

            f32x4 acc = {0.f, 0.f, 0.f, 0.f};
            #pragma unroll 4
            for (int k0 = 0; k0 < Dm; k0 += 32) {
                bf16x8 a = *(const bf16x8*)(Ap + k0);
                bf16x8 b = *(const bf16x8*)(Bp + k0);
                acc = __builtin_amdgcn_mfma_f32_16x16x32_bf16(a, b, acc, 0, 0, 0);
            }

            int orow = row0 + (kg << 2);
            float bb = bo[col0 + r];
            #pragma unroll
            for (int t = 0; t < 4; ++t)
                out[(orow + t) * Dm + col0 + r] = acc[t] + bb;
        }
    }
}

extern "C" void kernel_launch(void* const* d_in, const int* in_sizes, int n_in,
                              void* d_out, int out_size, void* d_ws, size_t ws_size,
                              hipStream_t stream) {
    const float* hs    = (const float*)d_in[0];
    const float* mask  = (const float*)d_in[1];
    const float* Wq    = (const float*)d_in[2];
    const float* bq    = (const float*)d_in[3];
    const float* Wk    = (const float*)d_in[4];
    const float* bk    = (const float*)d_in[5];
    const float* Wv    = (const float*)d_in[6];
    const float* bv    = (const float*)d_in[7];
    const float* Wo    = (const float*)d_in[8];
    const float* bo    = (const float*)d_in[9];
    const float* gamma = (const float*)d_in[10];
    const float* alpha = (const float*)d_in[11];
    float* out = (float*)d_out;

    char* base = (char*)d_ws;
    half_t* QT  = (half_t*)(base);                     // 0.5 MB
    half_t* KT  = QT + S * Dm;                         // 0.5 MB
    half_t* V16 = KT + S * Dm;                         // 0.5 MB
    __bf16* Abf = (__bf16*)(V16 + S * Dm);             // 0.5 MB
    __bf16* T0  = Abf + S * Dm;                        // 0.5 MB each
    __bf16* T1  = T0 + S * Dm;
    __bf16* T2  = T1 + S * Dm;
    __bf16* T3  = T2 + S * Dm;
    __bf16* Cbf = T3 + S * Dm;                         // 0.5 MB
    unsigned* cnt = (unsigned*)(base + (5u << 20));    // barrier counters

    hipMemsetAsync(cnt, 0, 4 * sizeof(unsigned), stream);
    hipLaunchKernelGGL(mega_kernel, dim3(NBLK), dim3(512), 0, stream,
                       hs, Wq, bq, Wk, bk, Wv, bv, Wo, bo,
                       mask, gamma, alpha,
                       Abf, T0, T1, T2, T3, QT, KT, V16, Cbf, out, cnt);
}

// Round 27
// 46.758 us; speedup vs baseline: 6.1642x; 4.7551x over previous
//
#include <hip/hip_runtime.h>

#define S 512
#define Dm 512

typedef __bf16 bf16x8 __attribute__((ext_vector_type(8)));
typedef float f32x4 __attribute__((ext_vector_type(4)));
typedef _Float16 half_t;
typedef half_t h2 __attribute__((ext_vector_type(2)));
typedef half_t h4 __attribute__((ext_vector_type(4)));

static __device__ __forceinline__ h2 habs2(h2 x) {
    unsigned u = __builtin_bit_cast(unsigned, x) & 0x7FFF7FFFu;
    return __builtin_bit_cast(h2, u);
}
static __device__ __forceinline__ h2 hmax2(h2 a, h2 b) {
    h2 r;
    asm("v_pk_max_f16 %0, %1, %2" : "=v"(r) : "v"(a), "v"(b));
    return r;
}

// ---------------- prep: hs->bf16 ; W->WT bf16 ----------------
__global__ __launch_bounds__(256) void prep_kernel(
    const float* __restrict__ hs,
    const float* __restrict__ W0, const float* __restrict__ W1,
    const float* __restrict__ W2, const float* __restrict__ W3,
    __bf16* __restrict__ Abf,
    __bf16* __restrict__ T0, __bf16* __restrict__ T1,
    __bf16* __restrict__ T2, __bf16* __restrict__ T3)
{
    __shared__ __bf16 Tl[64][72];
    int u = threadIdx.x;
    if (blockIdx.x < 128) {
        int i = (blockIdx.x * 256 + u) * 8;
        float4 x0 = *(const float4*)(hs + i);
        float4 x1 = *(const float4*)(hs + i + 4);
        bf16x8 y;
        y[0] = (__bf16)x0.x; y[1] = (__bf16)x0.y; y[2] = (__bf16)x0.z; y[3] = (__bf16)x0.w;
        y[4] = (__bf16)x1.x; y[5] = (__bf16)x1.y; y[6] = (__bf16)x1.z; y[7] = (__bf16)x1.w;
        *(bf16x8*)(Abf + i) = y;
        return;
    }
    int blk = blockIdx.x - 128;
    int m = blk >> 6;
    int t = blk & 63;
    const float* W = (m == 0) ? W0 : (m == 1) ? W1 : (m == 2) ? W2 : W3;
    __bf16* T = (m == 0) ? T0 : (m == 1) ? T1 : (m == 2) ? T2 : T3;
    int k0 = (t >> 3) << 6;
    int n0 = (t & 7) << 6;
    {
        int kk = u >> 4;
        int n4 = (u & 15) << 2;
        #pragma unroll
        for (int p = 0; p < 4; ++p) {
            int k = kk + (p << 4);
            float4 wv = *(const float4*)(W + (k0 + k) * Dm + n0 + n4);
            Tl[n4 + 0][k] = (__bf16)wv.x;
            Tl[n4 + 1][k] = (__bf16)wv.y;
            Tl[n4 + 2][k] = (__bf16)wv.z;
            Tl[n4 + 3][k] = (__bf16)wv.w;
        }
    }
    __syncthreads();
    {
        int n = u >> 2;
        int ks = (u & 3) << 4;
        uint4 d0 = *(const uint4*)&Tl[n][ks];
        uint4 d1 = *(const uint4*)&Tl[n][ks + 8];
        *(uint4*)(T + (n0 + n) * Dm + k0 + ks) = d0;
        *(uint4*)(T + (n0 + n) * Dm + k0 + ks + 8) = d1;
    }
}

// ---------------- bf16 MFMA GEMM ----------------
// TRANSQK=true: Q,K written TRANSPOSED fp16 (O^T[col][row], h4 stores); V written fp16 [row][col].
// TRANSQK=false: fp32 normal layout.
template<bool TRANSQK>
__global__ __launch_bounds__(256) void gemm_bf(
    const __bf16* __restrict__ Abf,
    const __bf16* __restrict__ T0, const __bf16* __restrict__ T1, const __bf16* __restrict__ T2,
    const float* __restrict__ b0, const float* __restrict__ b1, const float* __restrict__ b2,
    void* __restrict__ O0, void* __restrict__ O1, void* __restrict__ O2)
{
    int blk = blockIdx.x;
    int m = blk >> 8;
    int tile = blk & 255;
    const __bf16* T = (m == 0) ? T0 : (m == 1) ? T1 : T2;
    const float* bias = (m == 0) ? b0 : (m == 1) ? b1 : b2;
    void* Ov = (m == 0) ? O0 : (m == 1) ? O1 : O2;
    int rt = tile >> 4, ct = tile & 15;

    int u = threadIdx.x;
    int w = u >> 6, lane = u & 63;
    int r = lane & 15, kg = lane >> 4;

    int row0 = (rt << 5) + ((w >> 1) << 4);
    int col0 = (ct << 5) + ((w & 1) << 4);

    const __bf16* Ap = Abf + (row0 + r) * Dm + (kg << 3);
    const __bf16* Bp = T + (col0 + r) * Dm + (kg << 3);

    f32x4 acc = {0.f, 0.f, 0.f, 0.f};

    #pragma unroll 4
    for (int k0 = 0; k0 < Dm; k0 += 32) {
        bf16x8 a = *(const bf16x8*)(Ap + k0);
        bf16x8 b = *(const bf16x8*)(Bp + k0);
        acc = __builtin_amdgcn_mfma_f32_16x16x32_bf16(a, b, acc, 0, 0, 0);
    }

    int orow = row0 + (kg << 2);
    float bb = bias[col0 + r];

    if constexpr (TRANSQK) {
        if (m < 2) {
            half_t* O = (half_t*)Ov;
            h4 o;
            o[0] = (half_t)(acc[0] + bb);
            o[1] = (half_t)(acc[1] + bb);
            o[2] = (half_t)(acc[2] + bb);
            o[3] = (half_t)(acc[3] + bb);
            *(h4*)(O + (col0 + r) * S + orow) = o;
        } else {
            half_t* V = (half_t*)Ov;
            #pragma unroll
            for (int t = 0; t < 4; ++t)
                V[(orow + t) * Dm + col0 + r] = (half_t)(acc[t] + bb);
        }
        return;
    }
    float* O = (float*)Ov;
    #pragma unroll
    for (int t = 0; t < 4; ++t)
        O[(orow + t) * Dm + col0 + r] = acc[t] + bb;
}

// ---------------- fused z' + ctx, packed-fp16 math ----------------
__global__ __launch_bounds__(512) void zctx_kernel(
    const half_t* __restrict__ QT, const half_t* __restrict__ KT, const half_t* __restrict__ V,
    const float* __restrict__ mask, const float* __restrict__ gamma,
    const float* __restrict__ alpha, __bf16* __restrict__ ctxb)
{
    int blk = blockIdx.x;
    int h  = blk >> 6;
    int it = blk & 63;
    int i0 = it << 3;
    int c0 = h << 6;

    int u = threadIdx.x;
    int w = u >> 6, lane = u & 63;
    int jj = (w << 6) + lane;

    __shared__ half_t zs[512][8];
    __shared__ float zpart[8][8];
    __shared__ float part[8][8][64];

    // ---- phase A ----
    const half_t* kcol = KT + (c0 * S) + jj;
    const half_t* qrow = QT + (c0 * S) + i0;

    h2 acc2[4] = {};
    #pragma unroll 8
    for (int d = 0; d < 64; ++d) {
        half_t kh = kcol[d * S];
        h2 k2 = {kh, kh};
        uint4 qu = *(const uint4*)(qrow + d * S);
        h2 q0 = __builtin_bit_cast(h2, qu.x);
        h2 q1 = __builtin_bit_cast(h2, qu.y);
        h2 q2 = __builtin_bit_cast(h2, qu.z);
        h2 q3 = __builtin_bit_cast(h2, qu.w);
        acc2[0] += habs2(q0 - k2);
        acc2[1] += habs2(q1 - k2);
        acc2[2] += habs2(q2 - k2);
        acc2[3] += habs2(q3 - k2);
    }

    float sc = 1.0f / (gamma[0] * 8.0f);
    float al = alpha[0];
    float madd = (1.0f - mask[jj]) * 1e6f;

    float zrs[8];
    h4 zlo, zhi;
    #pragma unroll
    for (int p = 0; p < 4; ++p) {
        float s0 = (float)acc2[p].x;
        float s1 = (float)acc2[p].y;
        float z0 = fminf(fmaxf(s0 * sc - al, 0.0f) + madd, 64.0f);
        float z1 = fminf(fmaxf(s1 * sc - al, 0.0f) + madd, 64.0f);
        half_t h0 = (half_t)z0, h1 = (half_t)z1;
        if (p < 2) { zlo[2 * p] = h0; zlo[2 * p + 1] = h1; }
        else       { zhi[2 * (p - 2)] = h0; zhi[2 * (p - 2) + 1] = h1; }
        zrs[2 * p] = (float)h0;
        zrs[2 * p + 1] = (float)h1;
    }
    *(h4*)&zs[jj][0] = zlo;
    *(h4*)&zs[jj][4] = zhi;

    #pragma unroll
    for (int r = 0; r < 8; ++r) {
        float v = zrs[r];
        v += __shfl_xor(v, 1, 64);
        v += __shfl_xor(v, 2, 64);
        v += __shfl_xor(v, 4, 64);
        v += __shfl_xor(v, 8, 64);
        v += __shfl_xor(v, 16, 64);
        v += __shfl_xor(v, 32, 64);
        zrs[r] = v;
    }
    if (lane == 0) {
        #pragma unroll
        for (int r = 0; r < 8; ++r) zpart[w][r] = zrs[r];
    }
    __syncthreads();

    // ---- phase B ----
    int wu = __builtin_amdgcn_readfirstlane(w);
    float accB[8] = {};

    #pragma unroll
    for (int cch = 0; cch < 4; ++cch) {
        int jg = (cch << 7) + (wu << 4);
        h2 c2[4] = {};
        #pragma unroll
        for (int t = 0; t < 16; ++t) {
            half_t vh = V[(jg + t) * Dm + c0 + lane];
            h2 v2 = {vh, vh};
            uint4 zu = *(const uint4*)&zs[jg + t][0];
            c2[0] += hmax2(v2, __builtin_bit_cast(h2, zu.x));
            c2[1] += hmax2(v2, __builtin_bit_cast(h2, zu.y));
            c2[2] += hmax2(v2, __builtin_bit_cast(h2, zu.z));
            c2[3] += hmax2(v2, __builtin_bit_cast(h2, zu.w));
        }
        #pragma unroll
        for (int p = 0; p < 4; ++p) {
            accB[2 * p]     += (float)c2[p].x;
            accB[2 * p + 1] += (float)c2[p].y;
        }
    }

    #pragma unroll
    for (int ii = 0; ii < 8; ++ii)
        part[w][ii][lane] = accB[ii];
    __syncthreads();

    {
        int ii = u >> 6;
        float s = 0.f;
        #pragma unroll
        for (int ww = 0; ww < 8; ++ww) s += part[ww][ii][lane];
        float zsum = 0.f;
        #pragma unroll
        for (int p = 0; p < 8; ++p) zsum += zpart[p][ii];
        ctxb[(i0 + ii) * Dm + c0 + lane] = (__bf16)(s - zsum);
    }
}

extern "C" void kernel_launch(void* const* d_in, const int* in_sizes, int n_in,
                              void* d_out, int out_size, void* d_ws, size_t ws_size,
                              hipStream_t stream) {
    const float* hs    = (const float*)d_in[0];
    const float* mask  = (const float*)d_in[1];
    const float* Wq    = (const float*)d_in[2];
    const float* bq    = (const float*)d_in[3];
    const float* Wk    = (const float*)d_in[4];
    const float* bk    = (const float*)d_in[5];
    const float* Wv    = (const float*)d_in[6];
    const float* bv    = (const float*)d_in[7];
    const float* Wo    = (const float*)d_in[8];
    const float* bo    = (const float*)d_in[9];
    const float* gamma = (const float*)d_in[10];
    const float* alpha = (const float*)d_in[11];
    float* out = (float*)d_out;

    char* base = (char*)d_ws;
    half_t* QT  = (half_t*)(base);                     // 0.5 MB (transposed fp16)
    half_t* KT  = QT + S * Dm;                         // 0.5 MB
    half_t* V16 = KT + S * Dm;                         // 0.5 MB
    __bf16* Abf = (__bf16*)(V16 + S * Dm);             // 0.5 MB
    __bf16* T0  = Abf + S * Dm;                        // 0.5 MB each
    __bf16* T1  = T0 + S * Dm;
    __bf16* T2  = T1 + S * Dm;
    __bf16* T3  = T2 + S * Dm;
    __bf16* Cbf = T3 + S * Dm;                         // 0.5 MB

    hipLaunchKernelGGL(prep_kernel, dim3(384), dim3(256), 0, stream,
                       hs, Wq, Wk, Wv, Wo, Abf, T0, T1, T2, T3);
    hipLaunchKernelGGL((gemm_bf<true>), dim3(768), dim3(256), 0, stream,
                       Abf, T0, T1, T2, bq, bk, bv,
                       (void*)QT, (void*)KT, (void*)V16);
    hipLaunchKernelGGL(zctx_kernel, dim3(512), dim3(512), 0, stream,
                       QT, KT, V16, mask, gamma, alpha, Cbf);
    hipLaunchKernelGGL((gemm_bf<false>), dim3(256), dim3(256), 0, stream,
                       Cbf, T3, T3, T3, bo, bo, bo,
                       (void*)out, (void*)out, (void*)out);
}